// Round 6
// baseline (10359.002 us; speedup 1.0000x reference)
//
#include <hip/hip_runtime.h>

// Problem constants
#define TT 256
#define DD 128
#define HH 256
#define PP 2048
#define RB 16     // rows per block
#define NBLK 128  // 2048/16
#define NTH 512   // 8 waves

typedef _Float16 half8 __attribute__((ext_vector_type(8)));
typedef _Float16 half4 __attribute__((ext_vector_type(4)));
typedef float f32x4 __attribute__((ext_vector_type(4)));

#define MFMA16(a, b, c) __builtin_amdgcn_mfma_f32_16x16x32_f16((a), (b), (c), 0, 0, 0)
#define INV2048 (4.8828125e-4f)

__device__ __forceinline__ float sigmoidf_(float v) { return 1.0f / (1.0f + expf(-v)); }

// ---------------------------------------------------------------------------
// Weight fragments, prepacked for lane-linear streaming.
// Gate-tile order: tt = chunk*3 + gatetype (chunk = 16 units), 48 tiles.
// k-steps s: 0..3 = x-k (w_ih), 4..11 = h-k (w_hh). Sections [s][part][tile]:
// 512 halves per tile; element (m,k) at half index lane*8 + (k&7), lane = m + 16*(k>>3).
// part 0 = hi fp16, part 1 = (w - hi)*2048 fp16.
// pT[k*2048 + p] = protos[p][k].
__global__ void prep_kernel(const float* __restrict__ w_ih, const float* __restrict__ w_hh,
                            const float* __restrict__ protos,
                            _Float16* __restrict__ WF, float* __restrict__ pT) {
    int f = blockIdx.x * blockDim.x + threadIdx.x;
    if (f < 294912) {
        int s = f / 24576, rem = f % 24576;
        int tt = rem / 512, rem2 = rem % 512;
        int m = rem2 >> 5, kl = rem2 & 31;
        int grow = (tt % 3) * 256 + (tt / 3) * 16 + m;   // [r|z|n] within 16-unit chunk
        float v = (s < 4) ? w_ih[grow * DD + s * 32 + kl]
                          : w_hh[grow * HH + (s - 4) * 32 + kl];
        _Float16 hi = (_Float16)v;
        _Float16 lo = (_Float16)((v - (float)hi) * 2048.0f);
        int lane = m + 16 * (kl >> 3);
        int base = ((s * 2 + 0) * 48 + tt) * 512 + lane * 8 + (kl & 7);
        WF[base] = hi;
        WF[base + 48 * 512] = lo;   // part 1 section
    }
    if (f < HH * PP) pT[f] = protos[(f & (PP - 1)) * HH + (f >> 11)];
}

// ---------------------------------------------------------------------------
__launch_bounds__(NTH, 2)
__global__ void gru_kernel(const float* __restrict__ x,
                           const _Float16* __restrict__ WF,
                           const float* __restrict__ b_ih, const float* __restrict__ b_hh,
                           const float* __restrict__ pT,
                           int* __restrict__ out) {
    // Activation fragments: [buf][section = s*2+part][512 halves]; 48 KB.
    __shared__ __align__(16) _Float16 frag[2][24][512];
    __shared__ float hsF[HH][RB];          // final h fp32 for argmin (16 KB)
    __shared__ float redv[8][RB];
    __shared__ int   redi[8][RB];

    const int tid  = threadIdx.x;
    const int lane = tid & 63;
    const int w    = tid >> 6;          // wave id: owns tiles 6w..6w+5 = units 32w..32w+31
    const int row0 = blockIdx.x * RB;
    const int lane8 = lane * 8;
    const int t0    = w * 6;

    // Biases for this lane's 8 units: j = 32w + q*16 + ((lane>>4)*4) + r
    float bRv[2][4], bZv[2][4], bXNv[2][4], bHNv[2][4];
    #pragma unroll
    for (int q = 0; q < 2; ++q)
        #pragma unroll
        for (int r = 0; r < 4; ++r) {
            const int j = 32 * w + q * 16 + ((lane >> 4) << 2) + r;
            bRv[q][r]  = b_ih[j] + b_hh[j];
            bZv[q][r]  = b_ih[HH + j] + b_hh[HH + j];
            bXNv[q][r] = b_ih[2 * HH + j];
            bHNv[q][r] = b_hh[2 * HH + j];
        }

    float hprev[2][4];
    #pragma unroll
    for (int q = 0; q < 2; ++q)
        #pragma unroll
        for (int r = 0; r < 4; ++r) hprev[q][r] = 0.0f;

    // x loader mapping: row xn (0..15), 4 consecutive k at xk0
    const int xn = tid >> 5, xk0 = (tid & 31) * 4;
    const float* xptr = x + (size_t)(row0 + xn) * TT * DD + xk0;
    const int xsec = 2 * (xk0 >> 5);
    const int xidx = (((xk0 & 31) >> 3) * 16 + xn) * 8 + (xk0 & 7);

    // t=0: stage x_0 fragments; zero h fragments of buf 0 (h0 = 0)
    {
        const float4 v = *(const float4*)xptr;
        const float vv[4] = {v.x, v.y, v.z, v.w};
        _Float16 xh[4], xl[4];
        #pragma unroll
        for (int u = 0; u < 4; ++u) {
            xh[u] = (_Float16)vv[u];
            xl[u] = (_Float16)((vv[u] - (float)xh[u]) * 2048.0f);
        }
        *(half4*)&frag[0][xsec][xidx]     = half4{xh[0], xh[1], xh[2], xh[3]};
        *(half4*)&frag[0][xsec + 1][xidx] = half4{xl[0], xl[1], xl[2], xl[3]};
        // zero h sections (8..23): 8192 halves, 16 per thread
        _Float16* hz = &frag[0][8][0];
        *(half8*)(hz + tid * 16) = half8{0, 0, 0, 0, 0, 0, 0, 0};
        *(half8*)(hz + tid * 16 + 8) = half8{0, 0, 0, 0, 0, 0, 0, 0};
    }
    __syncthreads();

    const half8* __restrict__ WH = (const half8*)WF;   // 64 half8 per tile-section

    for (int t = 0; t < TT; ++t) {
        const int cur = t & 1, nxtb = cur ^ 1;

        float4 pf;
        const bool havepf = (t + 1 < TT);
        if (havepf) pf = *(const float4*)(xptr + (size_t)(t + 1) * DD);

        f32x4 a1m[6], a1x[6], a2m[6], a2x[6];
        #pragma unroll
        for (int i = 0; i < 6; ++i) {
            a1m[i] = f32x4{0.f, 0.f, 0.f, 0.f}; a1x[i] = f32x4{0.f, 0.f, 0.f, 0.f};
            a2m[i] = f32x4{0.f, 0.f, 0.f, 0.f}; a2x[i] = f32x4{0.f, 0.f, 0.f, 0.f};
        }

        // ---- x-GEMM: k-steps 0..3 ----
        #pragma unroll
        for (int s = 0; s < 4; ++s) {
            const half8 bh = *(const half8*)&frag[cur][2 * s][lane8];
            const half8 bl = *(const half8*)&frag[cur][2 * s + 1][lane8];
            #pragma unroll
            for (int i = 0; i < 6; ++i) {
                const half8 wh = WH[((2 * s) * 48 + t0 + i) * 64 + lane];
                const half8 wl = WH[((2 * s + 1) * 48 + t0 + i) * 64 + lane];
                a1m[i] = MFMA16(wh, bh, a1m[i]);
                a1x[i] = MFMA16(wh, bl, a1x[i]);
                a1x[i] = MFMA16(wl, bh, a1x[i]);
            }
        }
        // ---- h-GEMM: k-steps 4..11 ----
        #pragma unroll
        for (int s = 4; s < 12; ++s) {
            const half8 bh = *(const half8*)&frag[cur][2 * s][lane8];
            const half8 bl = *(const half8*)&frag[cur][2 * s + 1][lane8];
            #pragma unroll
            for (int i = 0; i < 6; ++i) {
                const half8 wh = WH[((2 * s) * 48 + t0 + i) * 64 + lane];
                const half8 wl = WH[((2 * s + 1) * 48 + t0 + i) * 64 + lane];
                a2m[i] = MFMA16(wh, bh, a2m[i]);
                a2x[i] = MFMA16(wh, bl, a2x[i]);
                a2x[i] = MFMA16(wl, bh, a2x[i]);
            }
        }

        // ---- gates + h update, fully in-register per lane ----
        // Lane holds rows n = lane&15, units j = 32w + q*16 + (lane>>4)*4 + r (acc reg r).
        #pragma unroll
        for (int q = 0; q < 2; ++q) {
            _Float16 hh_[4], hl_[4];
            #pragma unroll
            for (int r = 0; r < 4; ++r) {
                const float c1r = a1m[q * 3 + 0][r] + a1x[q * 3 + 0][r] * INV2048;
                const float c2r = a2m[q * 3 + 0][r] + a2x[q * 3 + 0][r] * INV2048;
                const float c1z = a1m[q * 3 + 1][r] + a1x[q * 3 + 1][r] * INV2048;
                const float c2z = a2m[q * 3 + 1][r] + a2x[q * 3 + 1][r] * INV2048;
                const float c1n = a1m[q * 3 + 2][r] + a1x[q * 3 + 2][r] * INV2048;
                const float c2n = a2m[q * 3 + 2][r] + a2x[q * 3 + 2][r] * INV2048;
                const float Rg = sigmoidf_(c1r + c2r + bRv[q][r]);
                const float Zg = sigmoidf_(c1z + c2z + bZv[q][r]);
                const float Ng = tanhf(c1n + bXNv[q][r] + Rg * (c2n + bHNv[q][r]));
                const float h = (1.0f - Zg) * Ng + Zg * hprev[q][r];
                hprev[q][r] = h;
                hh_[r] = (_Float16)h;
                hl_[r] = (_Float16)((h - (float)hh_[r]) * 2048.0f);
            }
            // write h fragments into next buffer (k = unit index j)
            const int jb  = 32 * w + q * 16 + ((lane >> 4) << 2);
            const int sec = 2 * (4 + (jb >> 5));
            const int idx = (((jb & 31) >> 3) * 16 + (lane & 15)) * 8 + (jb & 7);
            *(half4*)&frag[nxtb][sec][idx]     = half4{hh_[0], hh_[1], hh_[2], hh_[3]};
            *(half4*)&frag[nxtb][sec + 1][idx] = half4{hl_[0], hl_[1], hl_[2], hl_[3]};
        }

        // ---- stage x_{t+1} fragments ----
        if (havepf) {
            const float vv[4] = {pf.x, pf.y, pf.z, pf.w};
            _Float16 xh[4], xl[4];
            #pragma unroll
            for (int u = 0; u < 4; ++u) {
                xh[u] = (_Float16)vv[u];
                xl[u] = (_Float16)((vv[u] - (float)xh[u]) * 2048.0f);
            }
            *(half4*)&frag[nxtb][xsec][xidx]     = half4{xh[0], xh[1], xh[2], xh[3]};
            *(half4*)&frag[nxtb][xsec + 1][xidx] = half4{xl[0], xl[1], xl[2], xl[3]};
        }
        __syncthreads();
    }

    // ---- final h -> LDS fp32 ----
    #pragma unroll
    for (int q = 0; q < 2; ++q)
        #pragma unroll
        for (int r = 0; r < 4; ++r) {
            const int j = 32 * w + q * 16 + ((lane >> 4) << 2) + r;
            hsF[j][lane & 15] = hprev[q][r];
        }
    __syncthreads();

    // ---- cdist^2 + argmin over P=2048: thread covers protos {tid, +512, +1024, +1536} ----
    float bv[16]; int bi[16];
    #pragma unroll
    for (int r = 0; r < 16; ++r) { bv[r] = 3.4e38f; bi[r] = 0; }
    for (int m = 0; m < 4; ++m) {
        const int p = m * 512 + tid;
        float d2[16];
        #pragma unroll
        for (int r = 0; r < 16; ++r) d2[r] = 0.f;
        #pragma unroll 2
        for (int k = 0; k < HH; ++k) {
            const float pv = pT[(size_t)k * PP + p];
            #pragma unroll
            for (int g4 = 0; g4 < 4; ++g4) {
                const float4 hv = *(const float4*)&hsF[k][g4 * 4];
                float d;
                d = hv.x - pv; d2[g4 * 4 + 0] += d * d;
                d = hv.y - pv; d2[g4 * 4 + 1] += d * d;
                d = hv.z - pv; d2[g4 * 4 + 2] += d * d;
                d = hv.w - pv; d2[g4 * 4 + 3] += d * d;
            }
        }
        #pragma unroll
        for (int r = 0; r < 16; ++r)
            if (d2[r] < bv[r]) { bv[r] = d2[r]; bi[r] = p; }  // ascending p: keeps lowest on tie
    }
    #pragma unroll
    for (int s = 1; s < 64; s <<= 1) {
        #pragma unroll
        for (int r = 0; r < 16; ++r) {
            const float ov = __shfl_xor(bv[r], s);
            const int   oi = __shfl_xor(bi[r], s);
            if (ov < bv[r] || (ov == bv[r] && oi < bi[r])) { bv[r] = ov; bi[r] = oi; }
        }
    }
    if (lane == 0) {
        #pragma unroll
        for (int r = 0; r < 16; ++r) { redv[w][r] = bv[r]; redi[w][r] = bi[r]; }
    }
    __syncthreads();
    if (tid < RB) {
        float v = redv[0][tid]; int idx = redi[0][tid];
        #pragma unroll
        for (int u = 1; u < 8; ++u) {
            const float ov = redv[u][tid]; const int oi = redi[u][tid];
            if (ov < v || (ov == v && oi < idx)) { v = ov; idx = oi; }
        }
        out[row0 + tid] = idx;
    }
}

extern "C" void kernel_launch(void* const* d_in, const int* in_sizes, int n_in,
                              void* d_out, int out_size, void* d_ws, size_t ws_size,
                              hipStream_t stream) {
    const float* x      = (const float*)d_in[0];
    const float* w_ih   = (const float*)d_in[1];
    const float* w_hh   = (const float*)d_in[2];
    const float* b_ih   = (const float*)d_in[3];
    const float* b_hh   = (const float*)d_in[4];
    const float* protos = (const float*)d_in[5];
    int* out = (int*)d_out;

    _Float16* WF = (_Float16*)d_ws;                 // 589824 halves = 1.125 MB
    float*    pT = (float*)((char*)d_ws + 589824 * sizeof(_Float16));  // 2 MB

    hipLaunchKernelGGL(prep_kernel, dim3((HH * PP + 255) / 256), dim3(256), 0, stream,
                       w_ih, w_hh, protos, WF, pT);
    hipLaunchKernelGGL(gru_kernel, dim3(NBLK), dim3(NTH), 0, stream,
                       x, WF, b_ih, b_hh, pT, out);
}